// Round 2
// baseline (149.844 us; speedup 1.0000x reference)
//
#include <hip/hip_runtime.h>
#include <hip/hip_bf16.h>

#define HID 2048
#define OUTN 4096
#define VOC 4096
#define MEMN 4096
#define MDIM 64
#define OPN 5

static __device__ __forceinline__ float wave_reduce(float v) {
    #pragma unroll
    for (int off = 32; off > 0; off >>= 1) v += __shfl_down(v, off, 64);
    return v;
}

// ---- Kernel 1: h_bar[i] = dot(memory[0], Wm_w[i]) + Wm_b[i] + hidden0[i]
__global__ void k_hbar(const float* __restrict__ Wm_w,
                       const float* __restrict__ Wm_b,
                       const float* __restrict__ memory,
                       const float* __restrict__ hidden0,
                       float* __restrict__ h_bar) {
    int wave = (blockIdx.x * blockDim.x + threadIdx.x) >> 6;
    int lane = threadIdx.x & 63;
    if (wave >= HID) return;
    float v = Wm_w[(size_t)wave * MDIM + lane] * memory[lane];
    v = wave_reduce(v);
    if (lane == 0)
        h_bar[wave] = v + Wm_b[wave] + hidden0[wave];
}

// ---- Kernel 2: h[i] = tanh(x.W_ih[i] + b_ih[i] + h_bar.W_hh[i] + b_hh[i])
__global__ void k_hidden(const float* __restrict__ W_ih,
                         const float* __restrict__ x,
                         const float* __restrict__ b_ih,
                         const float* __restrict__ W_hh,
                         const float* __restrict__ b_hh,
                         const float* __restrict__ h_bar,
                         float* __restrict__ h,
                         float* __restrict__ ht_out) {
    int row = (blockIdx.x * blockDim.x + threadIdx.x) >> 6;
    int lane = threadIdx.x & 63;
    if (row >= HID) return;
    float acc = 0.f;
    const float* wrow = W_ih + (size_t)row * VOC;
    for (int k = lane * 4; k < VOC; k += 64 * 4) {
        float4 w = *(const float4*)(wrow + k);
        float4 xv = *(const float4*)(x + k);
        acc += w.x * xv.x + w.y * xv.y + w.z * xv.z + w.w * xv.w;
    }
    const float* wrow2 = W_hh + (size_t)row * HID;
    for (int k = lane * 4; k < HID; k += 64 * 4) {
        float4 w = *(const float4*)(wrow2 + k);
        float4 hv = *(const float4*)(h_bar + k);
        acc += w.x * hv.x + w.y * hv.y + w.z * hv.z + w.w * hv.w;
    }
    acc = wave_reduce(acc);
    if (lane == 0) {
        float hv = tanhf(acc + b_ih[row] + b_hh[row]);
        h[row] = hv;
        ht_out[row] = hv;
    }
}

// ---- Kernel 3: fused output heads.
// rows [0,4096): output = sigmoid(h.Wy+b) -> d_out
// rows [4096,4160): new_elt = sigmoid(h.Wn+b) -> ws (f32)
// rows [4160,4165): wa logits = h.Wa+b -> ws (f32)
__global__ void k_heads(const float* __restrict__ Wy_w,
                        const float* __restrict__ Wy_b,
                        const float* __restrict__ Wn_w,
                        const float* __restrict__ Wn_b,
                        const float* __restrict__ Wa_w,
                        const float* __restrict__ Wa_b,
                        const float* __restrict__ h,
                        float* __restrict__ out,
                        float* __restrict__ new_elt,
                        float* __restrict__ wa_logits) {
    int row = (blockIdx.x * blockDim.x + threadIdx.x) >> 6;
    int lane = threadIdx.x & 63;
    if (row >= OUTN + MDIM + OPN) return;
    const float* wrow;
    if (row < OUTN)             wrow = Wy_w + (size_t)row * HID;
    else if (row < OUTN + MDIM) wrow = Wn_w + (size_t)(row - OUTN) * HID;
    else                        wrow = Wa_w + (size_t)(row - OUTN - MDIM) * HID;
    float acc = 0.f;
    for (int k = lane * 4; k < HID; k += 64 * 4) {
        float4 w = *(const float4*)(wrow + k);
        float4 hv = *(const float4*)(h + k);
        acc += w.x * hv.x + w.y * hv.y + w.z * hv.z + w.w * hv.w;
    }
    acc = wave_reduce(acc);
    if (lane == 0) {
        if (row < OUTN) {
            float v = acc + Wy_b[row];
            out[row] = 1.f / (1.f + expf(-v));
        } else if (row < OUTN + MDIM) {
            int r = row - OUTN;
            float v = acc + Wn_b[r];
            new_elt[r] = 1.f / (1.f + expf(-v));
        } else {
            int r = row - OUTN - MDIM;
            wa_logits[r] = acc + Wa_b[r];
        }
    }
}

// ---- Kernel 4: memory stencil update + softmax(a) recomputed per thread.
// mem[r] = (a0 + (r<M-1)*a4) * m[r+1 mod] + (a1 + (r>0)*a3) * m[r-1 mod]
//          + a2 * m[r]  (+ new_elt on row 0)
__global__ void k_mem(const float* __restrict__ m,
                      const float* __restrict__ wa,
                      const float* __restrict__ new_elt,
                      float* __restrict__ mem_out) {
    int idx = blockIdx.x * blockDim.x + threadIdx.x;
    if (idx >= MEMN * MDIM) return;
    float l0 = wa[0], l1 = wa[1], l2 = wa[2], l3 = wa[3], l4 = wa[4];
    float mx = fmaxf(fmaxf(fmaxf(l0, l1), fmaxf(l2, l3)), l4);
    float e0 = expf(l0 - mx), e1 = expf(l1 - mx), e2 = expf(l2 - mx),
          e3 = expf(l3 - mx), e4 = expf(l4 - mx);
    float inv = 1.f / (e0 + e1 + e2 + e3 + e4);
    float a0 = e0 * inv, a1 = e1 * inv, a2 = e2 * inv, a3 = e3 * inv, a4 = e4 * inv;

    int r = idx >> 6, c = idx & (MDIM - 1);
    float mc = m[idx];
    float mp = m[(size_t)((r + 1) & (MEMN - 1)) * MDIM + c];
    float mm = m[(size_t)((r - 1) & (MEMN - 1)) * MDIM + c];
    float cp = a0 + (r < MEMN - 1 ? a4 : 0.f);
    float cm = a1 + (r > 0 ? a3 : 0.f);
    float v = cp * mp + cm * mm + a2 * mc;
    if (r == 0) v += new_elt[c];
    mem_out[idx] = v;
}

extern "C" void kernel_launch(void* const* d_in, const int* in_sizes, int n_in,
                              void* d_out, int out_size, void* d_ws, size_t ws_size,
                              hipStream_t stream) {
    const float* input   = (const float*)d_in[0];
    const float* hidden0 = (const float*)d_in[1];
    const float* memory  = (const float*)d_in[2];
    const float* W_ih    = (const float*)d_in[3];
    const float* b_ih    = (const float*)d_in[4];
    const float* W_hh    = (const float*)d_in[5];
    const float* b_hh    = (const float*)d_in[6];
    const float* Wm_w    = (const float*)d_in[7];
    const float* Wm_b    = (const float*)d_in[8];
    const float* Wy_w    = (const float*)d_in[9];
    const float* Wy_b    = (const float*)d_in[10];
    const float* Wn_w    = (const float*)d_in[11];
    const float* Wn_b    = (const float*)d_in[12];
    const float* Wa_w    = (const float*)d_in[13];
    const float* Wa_b    = (const float*)d_in[14];

    float* ws      = (float*)d_ws;
    float* h_bar   = ws;          // 2048
    float* h       = ws + 2048;   // 2048
    float* wa      = ws + 4096;   // 5
    float* new_elt = ws + 4104;   // 64

    float* out_f = (float*)d_out;             // 4096
    float* ht_f  = (float*)d_out + OUTN;      // 2048
    float* mem_f = (float*)d_out + OUTN + HID; // 262144

    // 4 waves/block
    k_hbar<<<HID / 4, 256, 0, stream>>>(Wm_w, Wm_b, memory, hidden0, h_bar);
    k_hidden<<<HID / 4, 256, 0, stream>>>(W_ih, input, b_ih, W_hh, b_hh,
                                          h_bar, h, ht_f);
    int rows3 = OUTN + MDIM + OPN;
    k_heads<<<(rows3 + 3) / 4, 256, 0, stream>>>(Wy_w, Wy_b, Wn_w, Wn_b,
                                                 Wa_w, Wa_b, h, out_f,
                                                 new_elt, wa);
    k_mem<<<(MEMN * MDIM) / 256, 256, 0, stream>>>(memory, wa, new_elt, mem_f);
}

// Round 3
// 137.968 us; speedup vs baseline: 1.0861x; 1.0861x over previous
//
#include <hip/hip_runtime.h>
#include <hip/hip_bf16.h>

#define HID 2048
#define OUTN 4096
#define VOC 4096
#define MEMN 4096
#define MDIM 64
#define OPN 5

static __device__ __forceinline__ float wave_reduce(float v) {
    #pragma unroll
    for (int off = 32; off > 0; off >>= 1) v += __shfl_down(v, off, 64);
    return v;
}

// Block-level reduction: 256 threads = 4 waves.
static __device__ __forceinline__ float block_reduce(float v, float* red) {
    int lane = threadIdx.x & 63;
    int wid = threadIdx.x >> 6;
    v = wave_reduce(v);
    if (lane == 0) red[wid] = v;
    __syncthreads();
    return red[0] + red[1] + red[2] + red[3];  // valid in all threads
}

// ---- Kernel 1: h_bar[i] = dot(memory[0], Wm_w[i]) + Wm_b[i] + hidden0[i]
// wave-per-row; tiny (512 KB read).
__global__ __launch_bounds__(256) void k_hbar(
        const float* __restrict__ Wm_w,
        const float* __restrict__ Wm_b,
        const float* __restrict__ memory,
        const float* __restrict__ hidden0,
        float* __restrict__ h_bar) {
    int wave = (blockIdx.x * blockDim.x + threadIdx.x) >> 6;
    int lane = threadIdx.x & 63;
    if (wave >= HID) return;
    float v = Wm_w[(size_t)wave * MDIM + lane] * memory[lane];
    v = wave_reduce(v);
    if (lane == 0)
        h_bar[wave] = v + Wm_b[wave] + hidden0[wave];
}

// ---- Kernel 2: h[row] = tanh(x.W_ih[row] + b_ih + h_bar.W_hh[row] + b_hh)
// one block (256 threads) per row; fully unrolled passes -> many loads in flight.
__global__ __launch_bounds__(256) void k_hidden(
        const float* __restrict__ W_ih,
        const float* __restrict__ x,
        const float* __restrict__ b_ih,
        const float* __restrict__ W_hh,
        const float* __restrict__ b_hh,
        const float* __restrict__ h_bar,
        float* __restrict__ h,
        float* __restrict__ ht_out) {
    __shared__ float red[4];
    int row = blockIdx.x;
    int tid = threadIdx.x;
    float acc = 0.f;
    const float* wrow = W_ih + (size_t)row * VOC;
    #pragma unroll
    for (int p = 0; p < VOC / (256 * 4); ++p) {   // 4 passes
        int k = (p * 256 + tid) * 4;
        float4 w = *(const float4*)(wrow + k);
        float4 xv = *(const float4*)(x + k);
        acc += w.x * xv.x + w.y * xv.y + w.z * xv.z + w.w * xv.w;
    }
    const float* wrow2 = W_hh + (size_t)row * HID;
    #pragma unroll
    for (int p = 0; p < HID / (256 * 4); ++p) {   // 2 passes
        int k = (p * 256 + tid) * 4;
        float4 w = *(const float4*)(wrow2 + k);
        float4 hv = *(const float4*)(h_bar + k);
        acc += w.x * hv.x + w.y * hv.y + w.z * hv.z + w.w * hv.w;
    }
    float s = block_reduce(acc, red);
    if (tid == 0) {
        float hv = tanhf(s + b_ih[row] + b_hh[row]);
        h[row] = hv;
        ht_out[row] = hv;
    }
}

// ---- Kernel 3: fused output heads, one block per row.
// rows [0,4096): output = sigmoid(h.Wy+b) -> d_out
// rows [4096,4160): new_elt = sigmoid(h.Wn+b) -> ws
// rows [4160,4165): wa logits = h.Wa+b -> ws
__global__ __launch_bounds__(256) void k_heads(
        const float* __restrict__ Wy_w,
        const float* __restrict__ Wy_b,
        const float* __restrict__ Wn_w,
        const float* __restrict__ Wn_b,
        const float* __restrict__ Wa_w,
        const float* __restrict__ Wa_b,
        const float* __restrict__ h,
        float* __restrict__ out,
        float* __restrict__ new_elt,
        float* __restrict__ wa_logits) {
    __shared__ float red[4];
    int row = blockIdx.x;
    int tid = threadIdx.x;
    const float* wrow;
    if (row < OUTN)             wrow = Wy_w + (size_t)row * HID;
    else if (row < OUTN + MDIM) wrow = Wn_w + (size_t)(row - OUTN) * HID;
    else                        wrow = Wa_w + (size_t)(row - OUTN - MDIM) * HID;
    float acc = 0.f;
    #pragma unroll
    for (int p = 0; p < HID / (256 * 4); ++p) {   // 2 passes
        int k = (p * 256 + tid) * 4;
        float4 w = *(const float4*)(wrow + k);
        float4 hv = *(const float4*)(h + k);
        acc += w.x * hv.x + w.y * hv.y + w.z * hv.z + w.w * hv.w;
    }
    float s = block_reduce(acc, red);
    if (tid == 0) {
        if (row < OUTN) {
            float v = s + Wy_b[row];
            out[row] = 1.f / (1.f + expf(-v));
        } else if (row < OUTN + MDIM) {
            int r = row - OUTN;
            float v = s + Wn_b[r];
            new_elt[r] = 1.f / (1.f + expf(-v));
        } else {
            int r = row - OUTN - MDIM;
            wa_logits[r] = s + Wa_b[r];
        }
    }
}

// ---- Kernel 4: memory stencil update + softmax(a) recomputed per thread.
__global__ __launch_bounds__(256) void k_mem(
        const float* __restrict__ m,
        const float* __restrict__ wa,
        const float* __restrict__ new_elt,
        float* __restrict__ mem_out) {
    int idx = blockIdx.x * blockDim.x + threadIdx.x;
    if (idx >= MEMN * MDIM) return;
    float l0 = wa[0], l1 = wa[1], l2 = wa[2], l3 = wa[3], l4 = wa[4];
    float mx = fmaxf(fmaxf(fmaxf(l0, l1), fmaxf(l2, l3)), l4);
    float e0 = expf(l0 - mx), e1 = expf(l1 - mx), e2 = expf(l2 - mx),
          e3 = expf(l3 - mx), e4 = expf(l4 - mx);
    float inv = 1.f / (e0 + e1 + e2 + e3 + e4);
    float a0 = e0 * inv, a1 = e1 * inv, a2 = e2 * inv, a3 = e3 * inv, a4 = e4 * inv;

    int r = idx >> 6, c = idx & (MDIM - 1);
    float mc = m[idx];
    float mp = m[(size_t)((r + 1) & (MEMN - 1)) * MDIM + c];
    float mm = m[(size_t)((r - 1) & (MEMN - 1)) * MDIM + c];
    float cp = a0 + (r < MEMN - 1 ? a4 : 0.f);
    float cm = a1 + (r > 0 ? a3 : 0.f);
    float v = cp * mp + cm * mm + a2 * mc;
    if (r == 0) v += new_elt[c];
    mem_out[idx] = v;
}

extern "C" void kernel_launch(void* const* d_in, const int* in_sizes, int n_in,
                              void* d_out, int out_size, void* d_ws, size_t ws_size,
                              hipStream_t stream) {
    const float* input   = (const float*)d_in[0];
    const float* hidden0 = (const float*)d_in[1];
    const float* memory  = (const float*)d_in[2];
    const float* W_ih    = (const float*)d_in[3];
    const float* b_ih    = (const float*)d_in[4];
    const float* W_hh    = (const float*)d_in[5];
    const float* b_hh    = (const float*)d_in[6];
    const float* Wm_w    = (const float*)d_in[7];
    const float* Wm_b    = (const float*)d_in[8];
    const float* Wy_w    = (const float*)d_in[9];
    const float* Wy_b    = (const float*)d_in[10];
    const float* Wn_w    = (const float*)d_in[11];
    const float* Wn_b    = (const float*)d_in[12];
    const float* Wa_w    = (const float*)d_in[13];
    const float* Wa_b    = (const float*)d_in[14];

    float* ws      = (float*)d_ws;
    float* h_bar   = ws;          // 2048
    float* h       = ws + 2048;   // 2048
    float* wa      = ws + 4096;   // 5
    float* new_elt = ws + 4104;   // 64

    float* out_f = (float*)d_out;              // 4096
    float* ht_f  = (float*)d_out + OUTN;       // 2048
    float* mem_f = (float*)d_out + OUTN + HID; // 262144

    k_hbar<<<HID / 4, 256, 0, stream>>>(Wm_w, Wm_b, memory, hidden0, h_bar);
    k_hidden<<<HID, 256, 0, stream>>>(W_ih, input, b_ih, W_hh, b_hh,
                                      h_bar, h, ht_f);
    int rows3 = OUTN + MDIM + OPN;
    k_heads<<<rows3, 256, 0, stream>>>(Wy_w, Wy_b, Wn_w, Wn_b,
                                       Wa_w, Wa_b, h, out_f,
                                       new_elt, wa);
    k_mem<<<(MEMN * MDIM) / 256, 256, 0, stream>>>(memory, wa, new_elt, mem_f);
}